// Round 13
// baseline (136.617 us; speedup 1.0000x reference)
//
#include <hip/hip_runtime.h>
#include <hip/hip_fp16.h>
#include <math.h>

// ---------------------------------------------------------------------------
// A3TGCN2 collapsed (H0 == 0 in every cell):
//   out[n,o] = sum_t p[t] * (1 - sigmoid(pre_z[n,t,o])) * tanh(pre_h[n,t,o])
//   pre_g[n,t,o] = sum_f Agg(X)[n,f,t] * Mg[o,f] + cg[o]
//   Agg = sym-normalized adjacency (+self loops) applied ONCE to raw X rows.
// R13 = R12 with the kB weight-bits bug fixed ((int)wbits, NOT
//   __float_as_int(wbits) which value-converts). Two-pass binned prep:
//   k0: coalesced edge scan -> LDS-binned into 8 dst-slice segments + pk zero
//       + weight prep.  kB: group (blockIdx&7, XCD-affine) drains its
//   contiguous segment densely into its L2-resident pk/slot slice.
//   k2/k3 byte-identical to R10 (k3 = proven 66.5us local optimum).
// ---------------------------------------------------------------------------

#define GATH16(EV, WT)                                                     \
  {                                                                        \
    unsigned voff = ((unsigned)(EV) << 9) | loff;                          \
    uint2 q = *(const uint2*)((const char*)Xh + voff);                     \
    __half2 ha = *(__half2*)&q.x;                                          \
    __half2 hb = *(__half2*)&q.y;                                          \
    acc.x = fmaf((WT), __low2float(ha),  acc.x);                           \
    acc.y = fmaf((WT), __high2float(ha), acc.y);                           \
    acc.z = fmaf((WT), __low2float(hb),  acc.z);                           \
    acc.w = fmaf((WT), __high2float(hb), acc.w);                           \
  }

__device__ inline void do_prep(int g, int tid,
    const float* __restrict__ Wz, const float* __restrict__ bz,
    const float* __restrict__ Wh, const float* __restrict__ bh,
    const float* __restrict__ Lz, const float* __restrict__ lzb,
    const float* __restrict__ Lh, const float* __restrict__ lhb,
    const float* __restrict__ att,
    float* __restrict__ Mt, float* __restrict__ cvec, float* __restrict__ p) {
  const float* L  = g ? Lh  : Lz;
  const float* W  = g ? Wh  : Wz;
  const float* bb = g ? bh  : bz;
  const float* lb = g ? lhb : lzb;
  int o = tid & 31;
  for (int f = tid >> 5; f < 32; f += 8) {
    float s = 0.f;
    for (int k = 0; k < 32; ++k) s += L[o * 64 + k] * W[k * 32 + f];
    Mt[g * 1024 + f * 32 + o] = s;      // transposed [g][f][o]
  }
  if (tid < 32) {
    float c = lb[tid];
    for (int k = 0; k < 32; ++k) c += L[tid * 64 + k] * bb[k];
    cvec[g * 32 + tid] = c;
  }
  if (g == 0 && tid == 0) {
    float m = att[0];
    for (int t = 1; t < 8; ++t) m = fmaxf(m, att[t]);
    float e8[8], sm = 0.f;
    for (int t = 0; t < 8; ++t) { e8[t] = expf(att[t] - m); sm += e8[t]; }
    for (int t = 0; t < 8; ++t) p[t] = e8[t] / sm;
  }
}

// pass0: blocks [0,nzb): zero pk | [nzb,nzb+2): prep | rest: edge split.
// Split: 4 edges/thread, LDS-binned by dst slice g=c/slice, packed rec
// (w_bits<<32 | coff<<17 | r) appended to seg[g] via one cursor atomic per
// (block, g).
__global__ __launch_bounds__(256) void k0(
    const int* __restrict__ ei, const float* __restrict__ ew,
    unsigned long long* __restrict__ pk, int N2,
    unsigned long long* __restrict__ seg, int segcap, int* __restrict__ cur8,
    int slice, unsigned long long Mdiv,
    const float* __restrict__ Wz, const float* __restrict__ bz,
    const float* __restrict__ Wh, const float* __restrict__ bh,
    const float* __restrict__ Lz, const float* __restrict__ lzb,
    const float* __restrict__ Lh, const float* __restrict__ lhb,
    const float* __restrict__ att,
    float* __restrict__ Mt, float* __restrict__ cvec, float* __restrict__ p,
    int E, int nzb) {
  int b = blockIdx.x;
  int tid = threadIdx.x;
  if (b < nzb) {                      // ---- zero pk (16B stores) ----
    int i = b * 256 + tid;
    if (i < N2) ((ulonglong2*)pk)[i] = make_ulonglong2(0ull, 0ull);
    return;
  }
  b -= nzb;
  if (b < 2) { do_prep(b, tid, Wz, bz, Wh, bh, Lz, lzb, Lh, lhb, att, Mt, cvec, p); return; }
  b -= 2;

  __shared__ int lcnt[8];
  __shared__ int lbase[8];
  if (tid < 8) lcnt[tid] = 0;
  __syncthreads();

  int gk[4]; int lp[4]; unsigned long long rec[4];
  int base = b * 1024 + tid;
#pragma unroll
  for (int k = 0; k < 4; ++k) {
    int e = base + k * 256;
    gk[k] = -1;
    if (e < E) {
      int r = ei[e];
      int c = ei[E + e];
      float w = ew[e];
      int g = (int)(((unsigned long long)(unsigned)c * Mdiv) >> 48);
      int coff = c - g * slice;
      gk[k] = g;
      rec[k] = ((unsigned long long)__float_as_uint(w) << 32) |
               ((unsigned)coff << 17) | (unsigned)r;
      lp[k] = atomicAdd(&lcnt[g], 1);
    }
  }
  __syncthreads();
  if (tid < 8) lbase[tid] = atomicAdd(&cur8[tid], lcnt[tid]);
  __syncthreads();
#pragma unroll
  for (int k = 0; k < 4; ++k) {
    if (gk[k] >= 0) {
      int pos = lbase[gk[k]] + lp[k];
      if (pos < segcap)
        seg[(size_t)gk[k] * segcap + pos] = rec[k];
    }
  }
}

// passB: group g = blockIdx&7 drains its contiguous segment. Dense lanes,
// atomics + stores land in group g's own pk/slot slice (L2-resident).
__global__ __launch_bounds__(256) void kB(
    const unsigned long long* __restrict__ seg, int segcap,
    const int* __restrict__ cur8, unsigned long long* __restrict__ pk,
    int2* __restrict__ slot, int cap, int slice, int Kb) {
  int g = blockIdx.x & 7;
  int n = blockIdx.x >> 3;
  int cnt = cur8[g];
  if (cnt > segcap) cnt = segcap;
  const unsigned long long* s = seg + (size_t)g * segcap;
  int lo = g * slice;
  int stride = Kb * 256;
  for (int i = n * 256 + threadIdx.x; i < cnt; i += stride) {
    unsigned long long rec = s[i];
    int r    = (int)(rec & 0x1FFFFull);
    int coff = (int)((rec >> 17) & 0x7FFFull);
    unsigned wbits = (unsigned)(rec >> 32);
    float w = __uint_as_float(wbits);
    int c = lo + coff;
    unsigned wfx = (unsigned)(w * 16777216.0f + 0.5f);
    unsigned long long old =
        atomicAdd(pk + c, ((unsigned long long)wfx << 32) | 1ull);
    unsigned pos = (unsigned)(old & 0xffffffffull);
    if (pos < (unsigned)cap)
      slot[(size_t)c * cap + pos] = make_int2(r, (int)wbits);  // BIT copy (R12 bug fixed)
  }
}

// X -> fp16, pre-scaled by dinv[node] (recomputed inline from pk)
__global__ __launch_bounds__(256) void k2_conv(
    const float* __restrict__ X, const unsigned long long* __restrict__ pk,
    __half* __restrict__ Xh, long n8) {
  long i = blockIdx.x * (long)blockDim.x + threadIdx.x;
  if (i < n8) {
    int node = (int)(i >> 5);
    unsigned long long v = pk[node];
    float di = rsqrtf((float)(v >> 32) * (1.0f / 16777216.0f) + 1.0f);
    const float4* Xv = (const float4*)X;
    float4 a = Xv[2 * i], c = Xv[2 * i + 1];
    union { int4 i4; __half2 h[4]; } u;
    u.h[0] = __floats2half2_rn(di * a.x, di * a.y);
    u.h[1] = __floats2half2_rn(di * a.z, di * a.w);
    u.h[2] = __floats2half2_rn(di * c.x, di * c.y);
    u.h[3] = __floats2half2_rn(di * c.z, di * c.w);
    ((int4*)Xh)[i] = u.i4;
  }
}

// One wave per node (proven R5/R10 form). Xh = dinv*X:
// agg = di * ( Xh[node] + sum_e w_e * Xh[src_e] )
__global__ __launch_bounds__(64) void k3_main(
    const __half* __restrict__ Xh, const unsigned long long* __restrict__ pk,
    const int2* __restrict__ slot, int cap,
    const float* __restrict__ Mt, const float* __restrict__ cvec,
    const float* __restrict__ p, float* __restrict__ out) {
  int node = blockIdx.x;
  int l = threadIdx.x;
  __shared__ float ax[256];

  unsigned long long v = pk[node];
  int cnt = (int)(v & 0xffffffffull);
  if (cnt > cap) cnt = cap;
  float di = rsqrtf((float)(v >> 32) * (1.0f / 16777216.0f) + 1.0f);

  float4 acc = make_float4(0.f, 0.f, 0.f, 0.f);
  unsigned loff = (unsigned)l << 3;

  GATH16(node, 1.0f);                            // self (Xh already has dinv)
  const int2* row = slot + (size_t)node * cap;
  int j = 0;
  for (; j + 7 < cnt; j += 8) {
    int2 e0 = row[j],     e1 = row[j + 1], e2 = row[j + 2], e3 = row[j + 3];
    int2 e4 = row[j + 4], e5 = row[j + 5], e6 = row[j + 6], e7 = row[j + 7];
    GATH16(e0.x, __int_as_float(e0.y));
    GATH16(e1.x, __int_as_float(e1.y));
    GATH16(e2.x, __int_as_float(e2.y));
    GATH16(e3.x, __int_as_float(e3.y));
    GATH16(e4.x, __int_as_float(e4.y));
    GATH16(e5.x, __int_as_float(e5.y));
    GATH16(e6.x, __int_as_float(e6.y));
    GATH16(e7.x, __int_as_float(e7.y));
  }
  for (; j < cnt; ++j) {
    int2 e0 = row[j];
    GATH16(e0.x, __int_as_float(e0.y));
  }
  acc.x *= di; acc.y *= di; acc.z *= di; acc.w *= di;

  ((float4*)ax)[l] = acc;                        // ax[f*8 + t] row layout
  __syncthreads();                               // single-wave: free

  int o = l & 31, g = l >> 5;
  float c = cvec[g * 32 + o];
  float pre[8];
#pragma unroll
  for (int t = 0; t < 8; ++t) pre[t] = c;

  const float*  M   = Mt + g * 1024;
  const float4* axv = (const float4*)ax;
#pragma unroll 8
  for (int f = 0; f < 32; ++f) {
    float  m  = M[f * 32 + o];
    float4 a0 = axv[f * 2];
    float4 a1 = axv[f * 2 + 1];
    pre[0] = fmaf(m, a0.x, pre[0]); pre[1] = fmaf(m, a0.y, pre[1]);
    pre[2] = fmaf(m, a0.z, pre[2]); pre[3] = fmaf(m, a0.w, pre[3]);
    pre[4] = fmaf(m, a1.x, pre[4]); pre[5] = fmaf(m, a1.y, pre[5]);
    pre[6] = fmaf(m, a1.z, pre[6]); pre[7] = fmaf(m, a1.w, pre[7]);
  }

  float vv[8];
  if (g == 0) {
#pragma unroll
    for (int t = 0; t < 8; ++t)
      vv[t] = __builtin_amdgcn_rcpf(1.f + __expf(pre[t]));     // 1 - sigmoid
  } else {
#pragma unroll
    for (int t = 0; t < 8; ++t)
      vv[t] = 1.f - 2.f * __builtin_amdgcn_rcpf(__expf(2.f * pre[t]) + 1.f);
  }

  float res = 0.f;
#pragma unroll
  for (int t = 0; t < 8; ++t) {
    float other = __shfl(vv[t], l ^ 32);
    res += p[t] * vv[t] * other;
  }
  if (g == 0) out[(size_t)node * 32 + o] = res;
}

// ======================= launcher =======================

extern "C" void kernel_launch(void* const* d_in, const int* in_sizes, int n_in,
                              void* d_out, int out_size, void* d_ws, size_t ws_size,
                              hipStream_t stream) {
  const float* X   = (const float*)d_in[0];
  const int*   ei  = (const int*)d_in[1];    // (2,E) int32 (jax x64 off)
  const float* ew  = (const float*)d_in[2];
  const float* Wz  = (const float*)d_in[3];
  const float* bz  = (const float*)d_in[4];
  const float* Wh  = (const float*)d_in[7];
  const float* bh  = (const float*)d_in[8];
  const float* Lz  = (const float*)d_in[9];
  const float* lzb = (const float*)d_in[10];
  const float* Lh  = (const float*)d_in[13];
  const float* lhb = (const float*)d_in[14];
  const float* att = (const float*)d_in[15];

  int N = in_sizes[0] / 256;   // F_IN * T = 256
  int E = in_sizes[2];
  (void)n_in; (void)out_size;

  long n8    = (long)N * 32;
  int  nbc   = (int)((n8 + 255) / 256);
  int  slice = (N + 7) / 8;                         // < 32768 for N <= 262144
  unsigned long long Mdiv =
      (unsigned long long)((((__uint128_t)1) << 48) / (unsigned)slice) + 1;
  int  segcap = (E >> 3) + (E >> 6) + 1024;         // ~14% margin over E/8

  size_t off = 0;
  auto al = [&](size_t b) { size_t q = off; off = (off + b + 255) & ~(size_t)255; return q; };
  size_t o_pk  = al((size_t)N * 8 + 16);
  size_t o_mt  = al(2048 * 4);
  size_t o_cv  = al(64 * 4);
  size_t o_p   = al(8 * 4);
  size_t o_c8  = al(64);
  size_t o_xh  = al((size_t)N * 256 * 2);
  size_t o_sg  = al((size_t)segcap * 8 * 8);
  size_t fixed = off;
  int cap = 0;
  for (int c : {64, 48, 32}) {
    if (fixed + (size_t)N * c * 8 <= ws_size) { cap = c; break; }
  }
  if (!cap) return;

  char* w = (char*)d_ws;
  unsigned long long* pk  = (unsigned long long*)(w + o_pk);
  float* Mt   = (float*)(w + o_mt);
  float* cvec = (float*)(w + o_cv);
  float* p    = (float*)(w + o_p);
  int*   cur8 = (int*)(w + o_c8);
  __half* Xh  = (__half*)(w + o_xh);
  unsigned long long* seg = (unsigned long long*)(w + o_sg);
  int2*  slot = (int2*)(w + fixed);

  int N2  = (N + 1) / 2;                         // ulonglong2 count (pk padded)
  int nzb = (N2 + 255) / 256;
  int nsp = (E + 1023) / 1024;
  int Kb  = 64;                                  // blocks per group in kB

  (void)hipMemsetAsync(cur8, 0, 64, stream);
  k0<<<nzb + 2 + nsp, 256, 0, stream>>>(ei, ew, pk, N2, seg, segcap, cur8,
                                        slice, Mdiv,
                                        Wz, bz, Wh, bh, Lz, lzb, Lh, lhb,
                                        att, Mt, cvec, p, E, nzb);
  kB<<<Kb * 8, 256, 0, stream>>>(seg, segcap, cur8, pk, slot, cap, slice, Kb);
  k2_conv<<<nbc, 256, 0, stream>>>(X, pk, Xh, n8);
  k3_main<<<N, 64, 0, stream>>>(Xh, pk, slot, cap, Mt, cvec, p,
                                (float*)d_out);
}

// Round 14
// 126.566 us; speedup vs baseline: 1.0794x; 1.0794x over previous
//
#include <hip/hip_runtime.h>
#include <hip/hip_fp16.h>
#include <math.h>

// ---------------------------------------------------------------------------
// A3TGCN2 collapsed (H0 == 0 in every cell):
//   out[n,o] = sum_t p[t] * (1 - sigmoid(pre_z[n,t,o])) * tanh(pre_h[n,t,o])
//   pre_g[n,t,o] = sum_f Agg(X)[n,f,t] * Mg[o,f] + cg[o]
//   Agg = sym-normalized adjacency (+self loops) applied ONCE to raw X rows.
// R14 = R10 verbatim (best measured: 126.5 us).
//   memset pk -> k1_part{prep | XCD-partitioned edge atomics+slot stores}
//   -> k2_conv (X -> fp16 * dinv) -> k3_main (1 wave/node gather + 2x32x32
//   GEMM from LDS + fused gates).
// Search closed: prep {plain/arena/nt/ILP/partition/binning} -> partition
// best; k3 {64thr/256thr/nt/4-wave} -> 64thr best. Both at access-pattern
// floors (random 8B placement; random 512B gathers over 8 incoherent L2s).
// ---------------------------------------------------------------------------

#define GATH16(EV, WT)                                                     \
  {                                                                        \
    unsigned voff = ((unsigned)(EV) << 9) | loff;                          \
    uint2 q = *(const uint2*)((const char*)Xh + voff);                     \
    __half2 ha = *(__half2*)&q.x;                                          \
    __half2 hb = *(__half2*)&q.y;                                          \
    acc.x = fmaf((WT), __low2float(ha),  acc.x);                           \
    acc.y = fmaf((WT), __high2float(ha), acc.y);                           \
    acc.z = fmaf((WT), __low2float(hb),  acc.z);                           \
    acc.w = fmaf((WT), __high2float(hb), acc.w);                           \
  }

__device__ inline void do_prep(int g, int tid,
    const float* __restrict__ Wz, const float* __restrict__ bz,
    const float* __restrict__ Wh, const float* __restrict__ bh,
    const float* __restrict__ Lz, const float* __restrict__ lzb,
    const float* __restrict__ Lh, const float* __restrict__ lhb,
    const float* __restrict__ att,
    float* __restrict__ Mt, float* __restrict__ cvec, float* __restrict__ p) {
  const float* L  = g ? Lh  : Lz;
  const float* W  = g ? Wh  : Wz;
  const float* bb = g ? bh  : bz;
  const float* lb = g ? lhb : lzb;
  int o = tid & 31;
  for (int f = tid >> 5; f < 32; f += 8) {
    float s = 0.f;
    for (int k = 0; k < 32; ++k) s += L[o * 64 + k] * W[k * 32 + f];
    Mt[g * 1024 + f * 32 + o] = s;      // transposed [g][f][o]
  }
  if (tid < 32) {
    float c = lb[tid];
    for (int k = 0; k < 32; ++k) c += L[tid * 64 + k] * bb[k];
    cvec[g * 32 + tid] = c;
  }
  if (g == 0 && tid == 0) {
    float m = att[0];
    for (int t = 1; t < 8; ++t) m = fmaxf(m, att[t]);
    float e8[8], sm = 0.f;
    for (int t = 0; t < 8; ++t) { e8[t] = expf(att[t] - m); sm += e8[t]; }
    for (int t = 0; t < 8; ++t) p[t] = e8[t] / sm;
  }
}

// blocks [0, 8K): edge groups (group = blockIdx & 7 ~ XCD); [8K, 8K+2): prep.
// Group g scans ALL edges, processes only dests in its slice -> each XCD's
// pk/slot slice stays L2-resident; col rescans are L3-hot.
__global__ __launch_bounds__(256) void k1_part(
    const int* __restrict__ ei, const float* __restrict__ ew,
    unsigned long long* __restrict__ pk, int2* __restrict__ slot, int cap,
    const float* __restrict__ Wz, const float* __restrict__ bz,
    const float* __restrict__ Wh, const float* __restrict__ bh,
    const float* __restrict__ Lz, const float* __restrict__ lzb,
    const float* __restrict__ Lh, const float* __restrict__ lhb,
    const float* __restrict__ att,
    float* __restrict__ Mt, float* __restrict__ cvec, float* __restrict__ p,
    int E, int N, int K) {
  int b = blockIdx.x;
  int tid = threadIdx.x;
  int nedge = K << 3;
  if (b >= nedge) {
    do_prep(b - nedge, tid, Wz, bz, Wh, bh, Lz, lzb, Lh, lhb, att, Mt, cvec, p);
    return;
  }
  int g = b & 7;                      // ~ XCD id under round-robin dispatch
  int n = b >> 3;
  int slice = (N + 7) >> 3;
  int lo = g * slice;
  int hi = lo + slice; if (hi > N) hi = N;
  int stride = K << 8;
  for (int e = (n << 8) + tid; e < E; e += stride) {
    int c = ei[E + e];
    if (c >= lo && c < hi) {
      int r = ei[e];
      float w = ew[e];
      unsigned wfx = (unsigned)(w * 16777216.0f + 0.5f);
      unsigned long long old =
          atomicAdd(pk + c, ((unsigned long long)wfx << 32) | 1ull);
      unsigned pos = (unsigned)(old & 0xffffffffull);
      if (pos < (unsigned)cap)
        slot[(size_t)c * cap + pos] = make_int2(r, __float_as_int(w));
    }
  }
}

// X -> fp16, pre-scaled by dinv[node] (recomputed inline from pk)
__global__ __launch_bounds__(256) void k2_conv(
    const float* __restrict__ X, const unsigned long long* __restrict__ pk,
    __half* __restrict__ Xh, long n8) {
  long i = blockIdx.x * (long)blockDim.x + threadIdx.x;
  if (i < n8) {
    int node = (int)(i >> 5);
    unsigned long long v = pk[node];
    float di = rsqrtf((float)(v >> 32) * (1.0f / 16777216.0f) + 1.0f);
    const float4* Xv = (const float4*)X;
    float4 a = Xv[2 * i], c = Xv[2 * i + 1];
    union { int4 i4; __half2 h[4]; } u;
    u.h[0] = __floats2half2_rn(di * a.x, di * a.y);
    u.h[1] = __floats2half2_rn(di * a.z, di * a.w);
    u.h[2] = __floats2half2_rn(di * c.x, di * c.y);
    u.h[3] = __floats2half2_rn(di * c.z, di * c.w);
    ((int4*)Xh)[i] = u.i4;
  }
}

// One wave per node (proven form). Xh = dinv*X:
// agg = di * ( Xh[node] + sum_e w_e * Xh[src_e] )
__global__ __launch_bounds__(64) void k3_main(
    const __half* __restrict__ Xh, const unsigned long long* __restrict__ pk,
    const int2* __restrict__ slot, int cap,
    const float* __restrict__ Mt, const float* __restrict__ cvec,
    const float* __restrict__ p, float* __restrict__ out) {
  int node = blockIdx.x;
  int l = threadIdx.x;
  __shared__ float ax[256];

  unsigned long long v = pk[node];
  int cnt = (int)(v & 0xffffffffull);
  if (cnt > cap) cnt = cap;
  float di = rsqrtf((float)(v >> 32) * (1.0f / 16777216.0f) + 1.0f);

  float4 acc = make_float4(0.f, 0.f, 0.f, 0.f);
  unsigned loff = (unsigned)l << 3;

  GATH16(node, 1.0f);                            // self (Xh already has dinv)
  const int2* row = slot + (size_t)node * cap;
  int j = 0;
  for (; j + 7 < cnt; j += 8) {
    int2 e0 = row[j],     e1 = row[j + 1], e2 = row[j + 2], e3 = row[j + 3];
    int2 e4 = row[j + 4], e5 = row[j + 5], e6 = row[j + 6], e7 = row[j + 7];
    GATH16(e0.x, __int_as_float(e0.y));
    GATH16(e1.x, __int_as_float(e1.y));
    GATH16(e2.x, __int_as_float(e2.y));
    GATH16(e3.x, __int_as_float(e3.y));
    GATH16(e4.x, __int_as_float(e4.y));
    GATH16(e5.x, __int_as_float(e5.y));
    GATH16(e6.x, __int_as_float(e6.y));
    GATH16(e7.x, __int_as_float(e7.y));
  }
  for (; j < cnt; ++j) {
    int2 e0 = row[j];
    GATH16(e0.x, __int_as_float(e0.y));
  }
  acc.x *= di; acc.y *= di; acc.z *= di; acc.w *= di;

  ((float4*)ax)[l] = acc;                        // ax[f*8 + t] row layout
  __syncthreads();                               // single-wave: free

  int o = l & 31, g = l >> 5;
  float c = cvec[g * 32 + o];
  float pre[8];
#pragma unroll
  for (int t = 0; t < 8; ++t) pre[t] = c;

  const float*  M   = Mt + g * 1024;
  const float4* axv = (const float4*)ax;
#pragma unroll 8
  for (int f = 0; f < 32; ++f) {
    float  m  = M[f * 32 + o];
    float4 a0 = axv[f * 2];
    float4 a1 = axv[f * 2 + 1];
    pre[0] = fmaf(m, a0.x, pre[0]); pre[1] = fmaf(m, a0.y, pre[1]);
    pre[2] = fmaf(m, a0.z, pre[2]); pre[3] = fmaf(m, a0.w, pre[3]);
    pre[4] = fmaf(m, a1.x, pre[4]); pre[5] = fmaf(m, a1.y, pre[5]);
    pre[6] = fmaf(m, a1.z, pre[6]); pre[7] = fmaf(m, a1.w, pre[7]);
  }

  float vv[8];
  if (g == 0) {
#pragma unroll
    for (int t = 0; t < 8; ++t)
      vv[t] = __builtin_amdgcn_rcpf(1.f + __expf(pre[t]));     // 1 - sigmoid
  } else {
#pragma unroll
    for (int t = 0; t < 8; ++t)
      vv[t] = 1.f - 2.f * __builtin_amdgcn_rcpf(__expf(2.f * pre[t]) + 1.f);
  }

  float res = 0.f;
#pragma unroll
  for (int t = 0; t < 8; ++t) {
    float other = __shfl(vv[t], l ^ 32);
    res += p[t] * vv[t] * other;
  }
  if (g == 0) out[(size_t)node * 32 + o] = res;
}

// ======================= launcher =======================

extern "C" void kernel_launch(void* const* d_in, const int* in_sizes, int n_in,
                              void* d_out, int out_size, void* d_ws, size_t ws_size,
                              hipStream_t stream) {
  const float* X   = (const float*)d_in[0];
  const int*   ei  = (const int*)d_in[1];    // (2,E) int32 (jax x64 off)
  const float* ew  = (const float*)d_in[2];
  const float* Wz  = (const float*)d_in[3];
  const float* bz  = (const float*)d_in[4];
  const float* Wh  = (const float*)d_in[7];
  const float* bh  = (const float*)d_in[8];
  const float* Lz  = (const float*)d_in[9];
  const float* lzb = (const float*)d_in[10];
  const float* Lh  = (const float*)d_in[13];
  const float* lhb = (const float*)d_in[14];
  const float* att = (const float*)d_in[15];

  int N = in_sizes[0] / 256;   // F_IN * T = 256
  int E = in_sizes[2];
  (void)n_in; (void)out_size;

  long n8  = (long)N * 32;
  int  nbc = (int)((n8 + 255) / 256);
  int  K   = (E + 2047) / 2048;

  size_t off = 0;
  auto al = [&](size_t b) { size_t q = off; off = (off + b + 255) & ~(size_t)255; return q; };
  size_t o_pk  = al((size_t)N * 8);
  size_t o_mt  = al(2048 * 4);
  size_t o_cv  = al(64 * 4);
  size_t o_p   = al(8 * 4);
  size_t o_xh  = al((size_t)N * 256 * 2);
  size_t fixed = off;
  int cap = 0;
  for (int c : {64, 48, 32}) {
    if (fixed + (size_t)N * c * 8 <= ws_size) { cap = c; break; }
  }
  if (!cap) return;

  char* w = (char*)d_ws;
  unsigned long long* pk = (unsigned long long*)(w + o_pk);
  float* Mt   = (float*)(w + o_mt);
  float* cvec = (float*)(w + o_cv);
  float* p    = (float*)(w + o_p);
  __half* Xh  = (__half*)(w + o_xh);
  int2*  slot = (int2*)(w + fixed);

  (void)hipMemsetAsync(pk, 0, (size_t)N * 8, stream);
  k1_part<<<K * 8 + 2, 256, 0, stream>>>(ei, ew, pk, slot, cap,
                                         Wz, bz, Wh, bh, Lz, lzb, Lh, lhb,
                                         att, Mt, cvec, p, E, N, K);
  k2_conv<<<nbc, 256, 0, stream>>>(X, pk, Xh, n8);
  k3_main<<<N, 64, 0, stream>>>(Xh, pk, slot, cap, Mt, cvec, p,
                                (float*)d_out);
}